// Round 7
// baseline (167.562 us; speedup 1.0000x reference)
//
#include <hip/hip_runtime.h>
#include <hip/hip_bf16.h>
#include <math.h>

#define NPTS 50000
#define BATCH 2
#define CIN 64
#define C2 64
#define KNN 16
#define NCELL 125
#define MTOT 800000

// wsf layout (floats):
// [0..6)       denom[b*3+c] = fp32(4*std)   (written by kfin2)
// [8..14)      mean[b*3+c]                  (written by kfin1)
// [16..1552)   PART1: pass-1 partials (b*3+c)*256 + s*8 + blk
// [2048..3584) PART2: pass-2 partials same indexing
// [4096..)     g[b][n][o] bf16 (12.8 MB)
// rel cache (19.2 MB) lives in d_out (fully overwritten by kmain afterwards).

__device__ __forceinline__ float bflo(unsigned int v) { return __uint_as_float(v << 16); }
__device__ __forceinline__ float bfhi(unsigned int v) { return __uint_as_float(v & 0xffff0000u); }

__device__ __forceinline__ int to_cell32(float s) {
    float x = __fmul_rn(__fsub_rn(__fmul_rn(__fadd_rn(s, 1.0f), 5.0f), 1.0f), 0.5f);
    x = rintf(x);                       // half-to-even, matches np.round
    x = fminf(fmaxf(x, 0.0f), 4.0f);
    return (int)x;
}

// exact numpy pairwise combine of 256 ordered partials (8 per group of 32)
__device__ __forceinline__ float reduce256(const float* __restrict__ p) {
    float v[32];
    #pragma unroll
    for (int s2 = 0; s2 < 32; ++s2) {
        const float* q = p + s2 * 8;
        float a  = __fadd_rn(__fadd_rn(q[0], q[1]), __fadd_rn(q[2], q[3]));
        float b2 = __fadd_rn(__fadd_rn(q[4], q[5]), __fadd_rn(q[6], q[7]));
        v[s2] = __fadd_rn(a, b2);
    }
    #pragma unroll
    for (int m = 16; m >= 1; m >>= 1)
        #pragma unroll
        for (int i = 0; i < 16; ++i)
            if (i < m) v[i] = __fadd_rn(v[2 * i], v[2 * i + 1]);
    return v[0];
}

// leaf bit-walk of numpy's pairwise split (n2 = n/2 - n/2%8), 8 levels, n=25000
__device__ __forceinline__ void leafwalk(int l, int& off, int& n) {
    off = 0; n = 25000;
    #pragma unroll
    for (int d = 7; d >= 0; --d) {
        int n2 = (n >> 1); n2 -= (n2 & 7);
        if ((l >> d) & 1) { off += n2; n -= n2; } else { n = n2; }
    }
}

// in-block finish: 8-chain shfl combine + 32-leaf pairwise tree
__device__ __forceinline__ void treefinish(float r, int t, int j, float* lsum,
                                           float* dst) {
    float a = __fadd_rn(r, __shfl_xor(r, 1));
    a = __fadd_rn(a, __shfl_xor(a, 2));
    a = __fadd_rn(a, __shfl_xor(a, 4));
    if (j == 0) lsum[t >> 3] = a;
    __syncthreads();
    for (int m = 16; m >= 1; m >>= 1) {
        float v = 0.0f;
        if (t < m) v = __fadd_rn(lsum[2 * t], lsum[2 * t + 1]);
        __syncthreads();
        if (t < m) lsum[t] = v;
        __syncthreads();
    }
    if (t == 0) *dst = lsum[0];
}

// ---------------- PW pass 1: coord-split, rel materialization ---------------
// grid (768, 2): bx = (c<<8) | (s*8+blk); 256 thr = 32 leaves * 8 chains
__global__ __launch_bounds__(256) void kpw1(const float* __restrict__ xyz,
                                            const int* __restrict__ knn,
                                            float* __restrict__ relc0,
                                            float* __restrict__ wsf) {
    __shared__ float lsum[32];
    int bx = blockIdx.x;
    int c = bx >> 8, r8 = bx & 255;
    int s = r8 >> 3, blk = r8 & 7;
    int b = blockIdx.y;
    const float* xs = xyz + (size_t)(b * 3 + c) * NPTS;
    const int* kb = knn + (size_t)b * NPTS * KNN;
    float* relc = relc0 + (size_t)(b * 3 + c) * MTOT;
    int t = threadIdx.x;
    int l = blk * 32 + (t >> 3);
    int j = t & 7;
    int off, n;
    leafwalk(l, off, n);
    int base = s * 25000 + off;
    float r = 0.0f;
    for (int i = j; i < n; i += 8) {
        int f = base + i;
        int kk = f / NPTS, nn = f - kk * NPTS;
        int jj = kb[nn * KNN + kk];
        float v = __fsub_rn(xs[jj], xs[nn]);
        relc[f] = v;
        r = __fadd_rn(r, v);
    }
    treefinish(r, t, j, lsum, &wsf[16 + ((size_t)(b * 3 + c) * 32 + s) * 8 + blk]);
}

// ---------------- kfin1: mean[6] ---------------------------------------------
__global__ void kfin1(float* __restrict__ wsf) {
    int bc = threadIdx.x;
    if (bc < 6) wsf[8 + bc] = reduce256(wsf + 16 + (size_t)bc * 256) / 800000.0f;
}

// ---------------- PW pass 2: coord-split, stream rel -------------------------
__global__ __launch_bounds__(256) void kpw2(const float* __restrict__ relc0,
                                            float* __restrict__ wsf) {
    __shared__ float lsum[32];
    int bx = blockIdx.x;
    int c = bx >> 8, r8 = bx & 255;
    int s = r8 >> 3, blk = r8 & 7;
    int b = blockIdx.y;
    const float* relc = relc0 + (size_t)(b * 3 + c) * MTOT;
    float mean = wsf[8 + b * 3 + c];
    int t = threadIdx.x;
    int l = blk * 32 + (t >> 3);
    int j = t & 7;
    int off, n;
    leafwalk(l, off, n);
    int base = s * 25000 + off;
    float r = 0.0f;
    for (int i = j; i < n; i += 8) {
        float d0 = __fsub_rn(relc[base + i], mean);
        r = __fadd_rn(r, __fmul_rn(d0, d0));
    }
    treefinish(r, t, j, lsum, &wsf[2048 + ((size_t)(b * 3 + c) * 32 + s) * 8 + blk]);
}

// ---------------- kfin2: denom[6] = 4*std ------------------------------------
__global__ void kfin2(float* __restrict__ wsf) {
    int bc = threadIdx.x;
    if (bc < 6) {
        float S = reduce256(wsf + 2048 + (size_t)bc * 256);
        wsf[bc] = __fmul_rn(4.0f, sqrtf(S / 799999.0f));
    }
}

// ---------------- kgemm: g = W*fea -> bf16 ----------------------------------
__global__ __launch_bounds__(256) void kgemm(const float* __restrict__ fea,
                                             const float* __restrict__ W,
                                             unsigned short* __restrict__ g) {
    int b = blockIdx.y;
    int n0 = blockIdx.x * 64;
    int nrem = NPTS - n0; if (nrem > 64) nrem = 64;
    __shared__ float flds[64][68];
    const float* fb = fea + (size_t)b * CIN * NPTS;
    int t = threadIdx.x;
    int j = t & 63, c0 = t >> 6;
    #pragma unroll
    for (int i = 0; i < 16; ++i) {
        int c = c0 + i * 4;
        flds[j][c] = (j < nrem) ? fb[(size_t)c * NPTS + n0 + j] : 0.0f;
    }
    int o = t & 63;
    float4 wr[16];
    #pragma unroll
    for (int i = 0; i < 16; ++i) wr[i] = ((const float4*)(W + o * CIN))[i];
    __syncthreads();
    int w = t >> 6;
    unsigned short* gb = g + ((size_t)b * NPTS + n0) * C2;
    #pragma unroll 1
    for (int p = w * 16; p < w * 16 + 16; ++p) {
        if (p >= nrem) break;
        float acc0 = 0, acc1 = 0, acc2 = 0, acc3 = 0;
        #pragma unroll
        for (int i = 0; i < 16; i += 4) {
            float4 f0 = *(const float4*)&flds[p][(i + 0) * 4];
            float4 f1 = *(const float4*)&flds[p][(i + 1) * 4];
            float4 f2 = *(const float4*)&flds[p][(i + 2) * 4];
            float4 f3 = *(const float4*)&flds[p][(i + 3) * 4];
            acc0 += wr[i+0].x*f0.x + wr[i+0].y*f0.y + wr[i+0].z*f0.z + wr[i+0].w*f0.w;
            acc1 += wr[i+1].x*f1.x + wr[i+1].y*f1.y + wr[i+1].z*f1.z + wr[i+1].w*f1.w;
            acc2 += wr[i+2].x*f2.x + wr[i+2].y*f2.y + wr[i+2].z*f2.z + wr[i+2].w*f2.w;
            acc3 += wr[i+3].x*f3.x + wr[i+3].y*f3.y + wr[i+3].z*f3.z + wr[i+3].w*f3.w;
        }
        float acc = (acc0 + acc1) + (acc2 + acc3);
        __hip_bfloat16 hb = __float2bfloat16(acc);
        gb[(size_t)p * C2 + o] = *(unsigned short*)&hb;
    }
}

// ---------------- kmain: lane-local gathers, 6 blocks/CU --------------------
__global__ __launch_bounds__(256, 6) void kmain(const float* __restrict__ xyz,
                                                const int* __restrict__ idx,
                                                const float* __restrict__ cb,
                                                const float* __restrict__ dw,
                                                const unsigned short* __restrict__ g,
                                                const float* __restrict__ wsf,
                                                float* __restrict__ out) {
    __shared__ unsigned int  dwp[NCELL * 32];    // [cell][u] bf16 pair, 16000B
    __shared__ unsigned char celllds[64 * KNN];  // 1024B
    __shared__ float         ctr[3][64];         // 768B
    __shared__ float         res[128 * 17];      // 8704B   (total ~26.5KB)
    int b = blockIdx.y;
    int n0 = blockIdx.x * 64;
    int t = threadIdx.x;
    int nrem = NPTS - n0; if (nrem > 64) nrem = 64;

    for (int i = t; i < NCELL * 32; i += 256) {
        int cell = i >> 5, u = i & 31;
        __hip_bfloat16 h0 = __float2bfloat16(dw[(2 * u)     * NCELL + cell]);
        __hip_bfloat16 h1 = __float2bfloat16(dw[(2 * u + 1) * NCELL + cell]);
        dwp[i] = (unsigned int)(*(unsigned short*)&h0) |
                 ((unsigned int)(*(unsigned short*)&h1) << 16);
    }
    const float* xb = xyz + (size_t)b * 3 * NPTS;
    if (t < 192) {
        int c = t >> 6, jx = t & 63;
        if (jx < nrem) ctr[c][jx] = xb[c * NPTS + n0 + jx];
    }
    const int* ib = idx + ((size_t)b * NPTS + n0) * KNN;
    __syncthreads();

    float dn0 = wsf[b * 3 + 0], dn1 = wsf[b * 3 + 1], dn2 = wsf[b * 3 + 2];
    for (int i = t; i < nrem * KNN; i += 256) {
        int p = i >> 4;
        int jx = ib[i];
        float sx = __fsub_rn(xb[jx],            ctr[0][p]) / dn0;
        float sy = __fsub_rn(xb[NPTS + jx],     ctr[1][p]) / dn1;
        float sz = __fsub_rn(xb[2 * NPTS + jx], ctr[2][p]) / dn2;
        celllds[i] = (unsigned char)((to_cell32(sz) * 5 + to_cell32(sy)) * 5 + to_cell32(sx));
    }
    __syncthreads();

    int w = t >> 6, h = (t >> 5) & 1, u = t & 31;
    int o0 = 2 * u, o1 = 2 * u + 1;
    float cb0 = cb[o0], cb1 = cb[o1];
    const unsigned short* gbp = g + (size_t)b * NPTS * C2;
    float* ob = out + (size_t)b * 128 * NPTS;

    #pragma unroll 1
    for (int chunk = 0; chunk < 4; ++chunk) {
        int pbase = chunk * 16;
        #pragma unroll 1
        for (int i = 0; i < 2; ++i) {
            int p = pbase + i * 8 + w * 2 + h;
            if (p < nrem) {
                const int* row = ib + p * KNN;
                unsigned int gnv = *(const unsigned int*)(gbp + (size_t)(n0 + p) * C2 + o0);
                float gn0 = bflo(gnv), gn1 = bfhi(gnv);
                int cell0 = celllds[p * KNN];
                unsigned int dp0 = dwp[cell0 * 32 + u];
                float k00 = bflo(dp0), k01 = bfhi(dp0);
                float ws0 = 0, ws1 = 0, gs0 = 0, gs1 = 0, sk0 = 0, sk1 = 0;
                #pragma unroll
                for (int k = 1; k < 16; ++k) {
                    int jj   = row[k];                         // broadcast, L1-hot
                    int cell = celllds[p * KNN + k];
                    unsigned int gv = *(const unsigned int*)(gbp + (size_t)jj * C2 + o0);
                    unsigned int dp = dwp[cell * 32 + u];
                    float g0 = bflo(gv), g1 = bfhi(gv);
                    float kw0 = bflo(dp), kw1 = bfhi(dp);
                    ws0 = fmaf(kw0, g0, ws0); ws1 = fmaf(kw1, g1, ws1);
                    gs0 += g0; gs1 += g1; sk0 += kw0; sk1 += kw1;
                }
                int pl = p & 15;
                res[o0 * 17 + pl]        = cb0 * (k00 + sk0) + gn0 * (k00 - sk0) + ws0;
                res[o1 * 17 + pl]        = cb1 * (k01 + sk1) + gn1 * (k01 - sk1) + ws1;
                res[(64 + o0) * 17 + pl] = cb0 + 0.0625f * (gs0 - 14.0f * gn0);
                res[(64 + o1) * 17 + pl] = cb1 + 0.0625f * (gs1 - 14.0f * gn1);
            }
        }
        __syncthreads();
        int rl = t >> 4;            // 0..15
        int jn = t & 15;
        int ncol = nrem - pbase; if (ncol > 16) ncol = 16;
        if (jn < ncol) {
            for (int r2 = rl; r2 < 128; r2 += 16)
                ob[(size_t)r2 * NPTS + n0 + pbase + jn] = res[r2 * 17 + jn];
        }
        __syncthreads();
    }
}

extern "C" void kernel_launch(void* const* d_in, const int* in_sizes, int n_in,
                              void* d_out, int out_size, void* d_ws, size_t ws_size,
                              hipStream_t stream) {
    const float* xyz   = (const float*)d_in[0];
    const float* fea   = (const float*)d_in[1];
    const int*   knn   = (const int*)d_in[2];
    const float* convw = (const float*)d_in[3];
    const float* convb = (const float*)d_in[4];
    const float* convdw= (const float*)d_in[5];
    float* out = (float*)d_out;
    float* wsf = (float*)d_ws;
    unsigned short* g = (unsigned short*)(wsf + 4096);
    float* relc = out;               // 4.8M floats scratch, fully overwritten by kmain

    int ntiles = (NPTS + 63) / 64;   // 782
    kpw1 <<<dim3(768, BATCH), 256, 0, stream>>>(xyz, knn, relc, wsf);
    kfin1<<<1, 64, 0, stream>>>(wsf);
    kpw2 <<<dim3(768, BATCH), 256, 0, stream>>>(relc, wsf);
    kfin2<<<1, 64, 0, stream>>>(wsf);
    kgemm<<<dim3(ntiles, BATCH), 256, 0, stream>>>(fea, convw, g);
    kmain<<<dim3(ntiles, BATCH), 256, 0, stream>>>(xyz, knn, convb, convdw, g, wsf, out);
}

// Round 8
// 164.164 us; speedup vs baseline: 1.0207x; 1.0207x over previous
//
#include <hip/hip_runtime.h>
#include <hip/hip_bf16.h>
#include <math.h>

#define NPTS 50000
#define BATCH 2
#define CIN 64
#define C2 64
#define KNN 16
#define NCELL 125
#define MTOT 800000

// wsf layout (floats):
// [16..1552)   PART1: pass-1 partials (b*3+c)*256 + s*8 + blk
// [2048..3584) PART2: pass-2 partials same indexing
// [4096..)     g[b][n][o] bf16 (12.8 MB)
// rel cache (19.2 MB) lives in d_out (fully overwritten by kmain afterwards).

__device__ __forceinline__ float bflo(unsigned int v) { return __uint_as_float(v << 16); }
__device__ __forceinline__ float bfhi(unsigned int v) { return __uint_as_float(v & 0xffff0000u); }

__device__ __forceinline__ int to_cell32(float s) {
    float x = __fmul_rn(__fsub_rn(__fmul_rn(__fadd_rn(s, 1.0f), 5.0f), 1.0f), 0.5f);
    x = rintf(x);                       // half-to-even, matches np.round
    x = fminf(fmaxf(x, 0.0f), 4.0f);
    return (int)x;
}

// leaf bit-walk of numpy's pairwise split (n2 = n/2 - n/2%8), 8 levels, n=25000
__device__ __forceinline__ void leafwalk(int l, int& off, int& n) {
    off = 0; n = 25000;
    #pragma unroll
    for (int d = 7; d >= 0; --d) {
        int n2 = (n >> 1); n2 -= (n2 & 7);
        if ((l >> d) & 1) { off += n2; n -= n2; } else { n = n2; }
    }
}

// in-block finish: 8-chain shfl combine + 32-leaf pairwise tree (exact numpy)
__device__ __forceinline__ void treefinish(float r, int t, int j, float* lsum,
                                           float* dst) {
    float a = __fadd_rn(r, __shfl_xor(r, 1));
    a = __fadd_rn(a, __shfl_xor(a, 2));
    a = __fadd_rn(a, __shfl_xor(a, 4));
    if (j == 0) lsum[t >> 3] = a;
    __syncthreads();
    for (int m = 16; m >= 1; m >>= 1) {
        float v = 0.0f;
        if (t < m) v = __fadd_rn(lsum[2 * t], lsum[2 * t + 1]);
        __syncthreads();
        if (t < m) lsum[t] = v;
        __syncthreads();
    }
    if (t == 0) *dst = lsum[0];
}

// ---------------- L1: pw1 (blocks 0..1535) + GEMM (blocks 1536..3099) ------
__global__ __launch_bounds__(256) void kfuse1(const float* __restrict__ xyz,
                                              const int* __restrict__ knn,
                                              const float* __restrict__ fea,
                                              const float* __restrict__ W,
                                              unsigned short* __restrict__ g,
                                              float* __restrict__ relc0,
                                              float* __restrict__ wsf) {
    __shared__ float sh[64 * 68];
    int bx = blockIdx.x;
    int t = threadIdx.x;
    if (bx < 1536) {
        // ---- PW pass 1: coord-split rel materialization + partial sums ----
        int b = bx / 768, rem = bx - b * 768;
        int c = rem >> 8, r8 = rem & 255;
        int s = r8 >> 3, blk = r8 & 7;
        const float* xs = xyz + (size_t)(b * 3 + c) * NPTS;
        const int* kb = knn + (size_t)b * NPTS * KNN;
        float* relc = relc0 + (size_t)(b * 3 + c) * MTOT;
        int l = blk * 32 + (t >> 3);
        int j = t & 7;
        int off, n;
        leafwalk(l, off, n);
        int base = s * 25000 + off;
        float r = 0.0f;
        for (int i = j; i < n; i += 8) {
            int f = base + i;
            int kk = f / NPTS, nn = f - kk * NPTS;
            int jj = kb[nn * KNN + kk];
            float v = __fsub_rn(xs[jj], xs[nn]);
            relc[f] = v;
            r = __fadd_rn(r, v);
        }
        treefinish(r, t, j, sh, &wsf[16 + ((size_t)(b * 3 + c) * 32 + s) * 8 + blk]);
    } else {
        // ---- GEMM role: g[b][n][o] = sum_c W[o][c]*fea[b][c][n] -> bf16 ----
        int i2 = bx - 1536;
        int b = (i2 >= 782);
        int tile = i2 - b * 782;
        int n0 = tile * 64;
        int nrem = NPTS - n0; if (nrem > 64) nrem = 64;
        float (*flds)[68] = (float (*)[68])sh;
        const float* fb = fea + (size_t)b * CIN * NPTS;
        int j = t & 63, c0 = t >> 6;
        #pragma unroll
        for (int i = 0; i < 16; ++i) {
            int c = c0 + i * 4;
            flds[j][c] = (j < nrem) ? fb[(size_t)c * NPTS + n0 + j] : 0.0f;
        }
        int o = t & 63;
        float4 wr[16];
        #pragma unroll
        for (int i = 0; i < 16; ++i) wr[i] = ((const float4*)(W + o * CIN))[i];
        __syncthreads();
        int w = t >> 6;
        unsigned short* gb = g + ((size_t)b * NPTS + n0) * C2;
        #pragma unroll 1
        for (int p = w * 16; p < w * 16 + 16; ++p) {
            if (p >= nrem) break;
            float acc0 = 0, acc1 = 0, acc2 = 0, acc3 = 0;
            #pragma unroll
            for (int i = 0; i < 16; i += 4) {
                float4 f0 = *(const float4*)&flds[p][(i + 0) * 4];
                float4 f1 = *(const float4*)&flds[p][(i + 1) * 4];
                float4 f2 = *(const float4*)&flds[p][(i + 2) * 4];
                float4 f3 = *(const float4*)&flds[p][(i + 3) * 4];
                acc0 += wr[i+0].x*f0.x + wr[i+0].y*f0.y + wr[i+0].z*f0.z + wr[i+0].w*f0.w;
                acc1 += wr[i+1].x*f1.x + wr[i+1].y*f1.y + wr[i+1].z*f1.z + wr[i+1].w*f1.w;
                acc2 += wr[i+2].x*f2.x + wr[i+2].y*f2.y + wr[i+2].z*f2.z + wr[i+2].w*f2.w;
                acc3 += wr[i+3].x*f3.x + wr[i+3].y*f3.y + wr[i+3].z*f3.z + wr[i+3].w*f3.w;
            }
            float acc = (acc0 + acc1) + (acc2 + acc3);
            __hip_bfloat16 hb = __float2bfloat16(acc);
            gb[(size_t)p * C2 + o] = *(unsigned short*)&hb;
        }
    }
}

// ---------------- L2: pw2 with inline bit-exact mean ------------------------
__global__ __launch_bounds__(256) void kpw2(const float* __restrict__ relc0,
                                            float* __restrict__ wsf) {
    __shared__ float lsum[32];
    __shared__ float meansh;
    int bx = blockIdx.x;
    int c = bx >> 8, r8 = bx & 255;
    int s = r8 >> 3, blk = r8 & 7;
    int b = blockIdx.y;
    int t = threadIdx.x;

    // inline kfin1: parallel reduce256 of PART1 (identical association)
    const float* P = wsf + 16 + (size_t)(b * 3 + c) * 256;
    if (t < 32) {
        const float* q = P + t * 8;
        float a  = __fadd_rn(__fadd_rn(q[0], q[1]), __fadd_rn(q[2], q[3]));
        float b2 = __fadd_rn(__fadd_rn(q[4], q[5]), __fadd_rn(q[6], q[7]));
        lsum[t] = __fadd_rn(a, b2);
    }
    __syncthreads();
    for (int m = 16; m >= 1; m >>= 1) {
        float v = 0.0f;
        if (t < m) v = __fadd_rn(lsum[2 * t], lsum[2 * t + 1]);
        __syncthreads();
        if (t < m) lsum[t] = v;
        __syncthreads();
    }
    if (t == 0) meansh = lsum[0] / 800000.0f;
    __syncthreads();
    float mean = meansh;

    const float* relc = relc0 + (size_t)(b * 3 + c) * MTOT;
    int l = blk * 32 + (t >> 3);
    int j = t & 7;
    int off, n;
    leafwalk(l, off, n);
    int base = s * 25000 + off;
    float r = 0.0f;
    for (int i = j; i < n; i += 8) {
        float d0 = __fsub_rn(relc[base + i], mean);
        r = __fadd_rn(r, __fmul_rn(d0, d0));
    }
    treefinish(r, t, j, lsum, &wsf[2048 + ((size_t)(b * 3 + c) * 32 + s) * 8 + blk]);
}

// ---------------- L3: kmain with inline bit-exact denom ---------------------
__global__ __launch_bounds__(256, 6) void kmain(const float* __restrict__ xyz,
                                                const int* __restrict__ idx,
                                                const float* __restrict__ cb,
                                                const float* __restrict__ dw,
                                                const unsigned short* __restrict__ g,
                                                const float* __restrict__ wsf,
                                                float* __restrict__ out) {
    __shared__ unsigned int  dwp[NCELL * 32];    // 16000B
    __shared__ unsigned char celllds[64 * KNN];  // 1024B
    __shared__ float         ctr[3][64];         // 768B
    __shared__ float         res[128 * 17];      // 8704B  (l3 tree aliases res)
    int b = blockIdx.y;
    int n0 = blockIdx.x * 64;
    int t = threadIdx.x;
    int nrem = NPTS - n0; if (nrem > 64) nrem = 64;

    // inline kfin2: parallel reduce256 of PART2 for 3 coords (in res space)
    float* l3 = res;                             // [c*32 + l]
    if (t < 96) {
        int c = t >> 5, l = t & 31;
        const float* q = wsf + 2048 + (size_t)(b * 3 + c) * 256 + l * 8;
        float a  = __fadd_rn(__fadd_rn(q[0], q[1]), __fadd_rn(q[2], q[3]));
        float b2 = __fadd_rn(__fadd_rn(q[4], q[5]), __fadd_rn(q[6], q[7]));
        l3[c * 32 + l] = __fadd_rn(a, b2);
    }
    __syncthreads();
    for (int m = 16; m >= 1; m >>= 1) {
        float v = 0.0f;
        int c = t >> 5, l = t & 31;
        if (t < 96 && l < m) v = __fadd_rn(l3[c * 32 + 2 * l], l3[c * 32 + 2 * l + 1]);
        __syncthreads();
        if (t < 96 && l < m) l3[c * 32 + l] = v;
        __syncthreads();
    }
    float dn0 = __fmul_rn(4.0f, sqrtf(l3[0]      / 799999.0f));
    float dn1 = __fmul_rn(4.0f, sqrtf(l3[32]     / 799999.0f));
    float dn2 = __fmul_rn(4.0f, sqrtf(l3[64]     / 799999.0f));
    __syncthreads();                             // res free for reuse after this

    for (int i = t; i < NCELL * 32; i += 256) {
        int cell = i >> 5, u = i & 31;
        __hip_bfloat16 h0 = __float2bfloat16(dw[(2 * u)     * NCELL + cell]);
        __hip_bfloat16 h1 = __float2bfloat16(dw[(2 * u + 1) * NCELL + cell]);
        dwp[i] = (unsigned int)(*(unsigned short*)&h0) |
                 ((unsigned int)(*(unsigned short*)&h1) << 16);
    }
    const float* xb = xyz + (size_t)b * 3 * NPTS;
    if (t < 192) {
        int c = t >> 6, jx = t & 63;
        if (jx < nrem) ctr[c][jx] = xb[c * NPTS + n0 + jx];
    }
    const int* ib = idx + ((size_t)b * NPTS + n0) * KNN;
    __syncthreads();

    for (int i = t; i < nrem * KNN; i += 256) {
        int p = i >> 4;
        int jx = ib[i];
        float sx = __fsub_rn(xb[jx],            ctr[0][p]) / dn0;
        float sy = __fsub_rn(xb[NPTS + jx],     ctr[1][p]) / dn1;
        float sz = __fsub_rn(xb[2 * NPTS + jx], ctr[2][p]) / dn2;
        celllds[i] = (unsigned char)((to_cell32(sz) * 5 + to_cell32(sy)) * 5 + to_cell32(sx));
    }
    __syncthreads();

    int w = t >> 6, h = (t >> 5) & 1, u = t & 31;
    int o0 = 2 * u, o1 = 2 * u + 1;
    float cb0 = cb[o0], cb1 = cb[o1];
    const unsigned short* gbp = g + (size_t)b * NPTS * C2;
    float* ob = out + (size_t)b * 128 * NPTS;

    #pragma unroll 1
    for (int chunk = 0; chunk < 4; ++chunk) {
        int pbase = chunk * 16;
        #pragma unroll 1
        for (int i = 0; i < 2; ++i) {
            int p = pbase + i * 8 + w * 2 + h;
            if (p < nrem) {
                const int* row = ib + p * KNN;
                unsigned int gnv = *(const unsigned int*)(gbp + (size_t)(n0 + p) * C2 + o0);
                float gn0 = bflo(gnv), gn1 = bfhi(gnv);
                int cell0 = celllds[p * KNN];
                unsigned int dp0 = dwp[cell0 * 32 + u];
                float k00 = bflo(dp0), k01 = bfhi(dp0);
                float ws0 = 0, ws1 = 0, gs0 = 0, gs1 = 0, sk0 = 0, sk1 = 0;
                #pragma unroll
                for (int k = 1; k < 16; ++k) {
                    int jj   = row[k];                         // broadcast, L1-hot
                    int cell = celllds[p * KNN + k];
                    unsigned int gv = *(const unsigned int*)(gbp + (size_t)jj * C2 + o0);
                    unsigned int dp = dwp[cell * 32 + u];
                    float g0 = bflo(gv), g1 = bfhi(gv);
                    float kw0 = bflo(dp), kw1 = bfhi(dp);
                    ws0 = fmaf(kw0, g0, ws0); ws1 = fmaf(kw1, g1, ws1);
                    gs0 += g0; gs1 += g1; sk0 += kw0; sk1 += kw1;
                }
                int pl = p & 15;
                res[o0 * 17 + pl]        = cb0 * (k00 + sk0) + gn0 * (k00 - sk0) + ws0;
                res[o1 * 17 + pl]        = cb1 * (k01 + sk1) + gn1 * (k01 - sk1) + ws1;
                res[(64 + o0) * 17 + pl] = cb0 + 0.0625f * (gs0 - 14.0f * gn0);
                res[(64 + o1) * 17 + pl] = cb1 + 0.0625f * (gs1 - 14.0f * gn1);
            }
        }
        __syncthreads();
        int rl = t >> 4;
        int jn = t & 15;
        int ncol = nrem - pbase; if (ncol > 16) ncol = 16;
        if (jn < ncol) {
            for (int r2 = rl; r2 < 128; r2 += 16)
                ob[(size_t)r2 * NPTS + n0 + pbase + jn] = res[r2 * 17 + jn];
        }
        __syncthreads();
    }
}

extern "C" void kernel_launch(void* const* d_in, const int* in_sizes, int n_in,
                              void* d_out, int out_size, void* d_ws, size_t ws_size,
                              hipStream_t stream) {
    const float* xyz   = (const float*)d_in[0];
    const float* fea   = (const float*)d_in[1];
    const int*   knn   = (const int*)d_in[2];
    const float* convw = (const float*)d_in[3];
    const float* convb = (const float*)d_in[4];
    const float* convdw= (const float*)d_in[5];
    float* out = (float*)d_out;
    float* wsf = (float*)d_ws;
    unsigned short* g = (unsigned short*)(wsf + 4096);
    float* relc = out;               // 4.8M floats scratch, fully overwritten by kmain

    int ntiles = (NPTS + 63) / 64;   // 782
    kfuse1<<<1536 + 1564, 256, 0, stream>>>(xyz, knn, fea, convw, g, relc, wsf);
    kpw2  <<<dim3(768, BATCH), 256, 0, stream>>>(relc, wsf);
    kmain <<<dim3(ntiles, BATCH), 256, 0, stream>>>(xyz, knn, convb, convdw, g, wsf, out);
}